// Round 6
// baseline (123.139 us; speedup 1.0000x reference)
//
#include <hip/hip_runtime.h>
#include <hip/hip_bf16.h>

typedef __attribute__((ext_vector_type(8))) short short8_t;
typedef __attribute__((ext_vector_type(4))) short short4_t;
typedef __attribute__((ext_vector_type(4))) float float4_t;

#define B_   4
#define C_   256
#define N_   4096
#define DQK  32
#define LOG2E 1.4426950408889634f

#define VMCNT4   asm volatile("s_waitcnt vmcnt(4)" ::: "memory")
#define LGKM0    asm volatile("s_waitcnt lgkmcnt(0)" ::: "memory")
#define SBAR     __builtin_amdgcn_s_barrier()
#define SCHEDB   __builtin_amdgcn_sched_barrier(0)

__device__ __forceinline__ unsigned short f2bf(float x) {
    union { float f; unsigned int u; } v; v.f = x;
    unsigned int r = v.u + 0x7FFFu + ((v.u >> 16) & 1u);   // RNE
    return (unsigned short)(r >> 16);
}
__device__ __forceinline__ unsigned short f2bf_hw(float x) {
    return __bfloat16_as_ushort(__float2bfloat16(x));      // hw RNE, pairs to cvt_pk
}

// ---------------- weight casts ----------------
__global__ __launch_bounds__(256) void cast_w_k(
        const float* __restrict__ Wq, const float* __restrict__ Wk,
        const float* __restrict__ Wv,
        unsigned short* __restrict__ Wqb, unsigned short* __restrict__ Wkb,
        unsigned short* __restrict__ Wvb) {
    int i = blockIdx.x * 256 + threadIdx.x;
    if (i < 8192)            Wqb[i] = f2bf(Wq[i]);
    else if (i < 16384)      Wkb[i - 8192] = f2bf(Wk[i - 8192]);
    else                     Wvb[i - 16384] = f2bf(Wv[i - 16384]);
}

// ---------------- pq / pk projection, reading x f32 [b][c][n] directly ----------------
// pq output pre-scaled by log2(e) so attention can use exp2 directly.
__global__ __launch_bounds__(256) void proj_qk_k(
        const float* __restrict__ q_in, const float* __restrict__ k_in,
        const unsigned short* __restrict__ Wqb, const unsigned short* __restrict__ Wkb,
        const float* __restrict__ bq, const float* __restrict__ bk,
        unsigned short* __restrict__ pqT, unsigned short* __restrict__ pkT) {
    int b = blockIdx.y, z = blockIdx.z;
    const float* X = z ? k_in : q_in;
    const unsigned short* W = z ? Wkb : Wqb;
    const float* bias = z ? bk : bq;
    unsigned short* P = z ? pkT : pqT;
    float scl = z ? 1.0f : LOG2E;
    int tid = threadIdx.x, wave = tid >> 6, lane = tid & 63, l15 = lane & 15, g = lane >> 4;
    int nb = blockIdx.x * 64 + wave * 16;
    float4_t acc0 = {0.f, 0.f, 0.f, 0.f}, acc1 = {0.f, 0.f, 0.f, 0.f};
    const float* Xcol = X + (size_t)b * C_ * N_ + nb + l15;
#pragma unroll
    for (int kk = 0; kk < 8; ++kk) {
        short8_t a;
#pragma unroll
        for (int j = 0; j < 8; ++j)
            a[j] = (short)f2bf(Xcol[(size_t)(kk * 32 + 8 * g + j) * N_]);
        short8_t b0 = *(const short8_t*)(W + (size_t)l15 * C_ + kk * 32 + 8 * g);
        short8_t b1 = *(const short8_t*)(W + (size_t)(16 + l15) * C_ + kk * 32 + 8 * g);
        acc0 = __builtin_amdgcn_mfma_f32_16x16x32_bf16(a, b0, acc0, 0, 0, 0);
        acc1 = __builtin_amdgcn_mfma_f32_16x16x32_bf16(a, b1, acc1, 0, 0, 0);
    }
#pragma unroll
    for (int r = 0; r < 4; ++r) {
        int n = nb + 4 * g + r;
        P[((size_t)b * N_ + n) * DQK + l15]      = f2bf((acc0[r] + bias[l15]) * scl);
        P[((size_t)b * N_ + n) * DQK + 16 + l15] = f2bf((acc1[r] + bias[16 + l15]) * scl);
    }
}

// ---------------- pv projection: pv[b][c][m'] = Wv x v + bv, keys pi-permuted ----------------
__global__ __launch_bounds__(256) void proj_v_k(
        const float* __restrict__ v_in, const unsigned short* __restrict__ Wvb,
        const float* __restrict__ bv, unsigned short* __restrict__ pv) {
    int b = blockIdx.y;
    int tid = threadIdx.x, wave = tid >> 6, lane = tid & 63, l15 = lane & 15, g = lane >> 4;
    int mb = blockIdx.x * 16;
    int m = mb + l15;
    int k32 = m & 31;
    int pcol = (k32 < 16) ? ((k32 >> 2) * 8 + (k32 & 3))
                          : (((k32 - 16) >> 2) * 8 + 4 + (k32 & 3));
    int mcol = (m & ~31) + pcol;
    float4_t acc[4];
#pragma unroll
    for (int i = 0; i < 4; ++i) acc[i] = (float4_t){0.f, 0.f, 0.f, 0.f};
    const float* Vcol = v_in + (size_t)b * C_ * N_ + mb + l15;
#pragma unroll
    for (int kk = 0; kk < 8; ++kk) {
        short8_t bf;
#pragma unroll
        for (int j = 0; j < 8; ++j)
            bf[j] = (short)f2bf(Vcol[(size_t)(kk * 32 + 8 * g + j) * N_]);
#pragma unroll
        for (int ct = 0; ct < 4; ++ct) {
            short8_t af = *(const short8_t*)(Wvb + (size_t)(wave * 64 + ct * 16 + l15) * C_ + kk * 32 + 8 * g);
            acc[ct] = __builtin_amdgcn_mfma_f32_16x16x32_bf16(af, bf, acc[ct], 0, 0, 0);
        }
    }
#pragma unroll
    for (int ct = 0; ct < 4; ++ct)
#pragma unroll
        for (int r = 0; r < 4; ++r) {
            int c = wave * 64 + ct * 16 + 4 * g + r;
            pv[((size_t)b * C_ + c) * N_ + mcol] = f2bf(acc[ct][r] + bv[c]);
        }
}

// ---------------- fused single-pass flash attention + normalize + residual ----------------
// 512 threads = 8 waves = 4 q-slices x 2 ch-halves. Wave owns 16 queries x 128
// channels; P stays in registers (swapped QK^T output == PV B-fragment). Each
// wave reads only its 128-ch half of the V tile -> 2x less LDS read than r5.
// V tile double-buffered (2x32KB), staged via global_load_lds 1 tile ahead.
__global__ __launch_bounds__(512, 2) void attn_fused_k(
        const unsigned short* __restrict__ pqT, const unsigned short* __restrict__ pkT,
        const unsigned short* __restrict__ pv, const float* __restrict__ v_in,
        const float* __restrict__ gamma, float* __restrict__ out) {
    __shared__ __align__(16) unsigned short VT[2][256][64];   // 64KB
    int b = blockIdx.z;
    int qb = blockIdx.x * 64;
    int tid = threadIdx.x, wave = tid >> 6, lane = tid & 63, l15 = lane & 15, g = lane >> 4;
    int wq = wave & 3, wc = wave >> 2;       // q-slice, ch-half
    int sw = (l15 & 7) << 4;
    int rl = lane >> 3, cp = lane & 7, cl = cp ^ rl;          // staging source permute
    const int nt = N_ / 64;

    short8_t qf = *(const short8_t*)(pqT + ((size_t)b * N_ + qb + wq * 16 + l15) * DQK + 8 * g);
    float4_t acc[8];
#pragma unroll
    for (int i = 0; i < 8; ++i) acc[i] = (float4_t){0.f, 0.f, 0.f, 0.f};
    float l_acc = 0.f;
    const float4_t zero4 = {0.f, 0.f, 0.f, 0.f};
    const unsigned short* pvb = pv + (size_t)b * C_ * N_;

#define LOADG(dst, ctbase)                                                    \
    _Pragma("unroll")                                                         \
    for (int i_ = 0; i_ < 4; ++i_) {                                          \
        const char* vrow_ = vb + (((ctbase) + i_) * 16 + l15) * 128;          \
        dst[i_][0] = *(const short8_t*)(vrow_ + ((16 * g) ^ sw));             \
        dst[i_][1] = *(const short8_t*)(vrow_ + ((64 + 16 * g) ^ sw));        \
    }
#define MFMAG(frag, ctbase)                                                   \
    _Pragma("unroll")                                                         \
    for (int i_ = 0; i_ < 4; ++i_) {                                          \
        acc[(ctbase) + i_] = __builtin_amdgcn_mfma_f32_16x16x32_bf16(frag[i_][0], pb0, acc[(ctbase) + i_], 0, 0, 0); \
        acc[(ctbase) + i_] = __builtin_amdgcn_mfma_f32_16x16x32_bf16(frag[i_][1], pb1, acc[(ctbase) + i_], 0, 0, 0); \
    }

    // ---- prologue: stage V(0) -> buf0 (wave stages rows i*64 + wave*8 + rl) ----
#pragma unroll
    for (int i = 0; i < 4; ++i) {
        int row0 = i * 64 + wave * 8;
        const unsigned short* src = pvb + (size_t)(row0 + rl) * N_ + 8 * cl;
        __builtin_amdgcn_global_load_lds(
            (const __attribute__((address_space(1))) unsigned int*)(const void*)src,
            (__attribute__((address_space(3))) unsigned int*)(void*)&VT[0][row0][0], 16, 0, 0);
    }
    short8_t kfc[4];
#pragma unroll
    for (int it = 0; it < 4; ++it)
        kfc[it] = *(const short8_t*)(pkT + ((size_t)b * N_ + 16 * it + l15) * DQK + 8 * g);
    VMCNT4; SCHEDB;          // V(0) landed (kf still in flight)
    SBAR;

    for (int t = 0; t < nt; ++t) {
        const int rb = t & 1;
        const int msn = (t + 1) * 64;
        // stage V(t+1) -> other buffer (fire-and-forget)
        if (t + 1 < nt) {
#pragma unroll
            for (int i = 0; i < 4; ++i) {
                int row0 = i * 64 + wave * 8;
                const unsigned short* src = pvb + (size_t)(row0 + rl) * N_ + msn + 8 * cl;
                __builtin_amdgcn_global_load_lds(
                    (const __attribute__((address_space(1))) unsigned int*)(const void*)src,
                    (__attribute__((address_space(3))) unsigned int*)(void*)&VT[rb ^ 1][row0][0], 16, 0, 0);
            }
        }
        SCHEDB;
        // ---- V-fragments for this wave's 128-ch half (16 ds_read_b128) ----
        const char* vb = (const char*)&VT[rb][0][0] + wc * 16384;
        short8_t vg0[4][2], vg1[4][2];
        LOADG(vg0, 0);
        LOADG(vg1, 4);
        // ---- QK: wave's 16 queries x 64 keys (swapped -> S^T) ----
        float4_t sv[4];
#pragma unroll
        for (int it = 0; it < 4; ++it)
            sv[it] = __builtin_amdgcn_mfma_f32_16x16x32_bf16(kfc[it], qf, zero4, 0, 0, 0);
        short8_t kfn[4];
        if (t + 1 < nt) {
#pragma unroll
            for (int it = 0; it < 4; ++it)
                kfn[it] = *(const short8_t*)(pkT + ((size_t)b * N_ + msn + 16 * it + l15) * DQK + 8 * g);
        }
        // ---- exp2 (pq pre-scaled by log2e; no max-subtraction) + pack ----
        float p[16];
#pragma unroll
        for (int it = 0; it < 4; ++it)
#pragma unroll
            for (int r = 0; r < 4; ++r)
                p[it * 4 + r] = exp2f(sv[it][r]);
        float s0 = (p[0] + p[1]) + (p[2] + p[3]);
        float s1 = (p[4] + p[5]) + (p[6] + p[7]);
        float s2 = (p[8] + p[9]) + (p[10] + p[11]);
        float s3 = (p[12] + p[13]) + (p[14] + p[15]);
        l_acc += (s0 + s1) + (s2 + s3);
        short8_t pb0, pb1;
#pragma unroll
        for (int j = 0; j < 4; ++j) {
            pb0[j]     = (short)f2bf_hw(p[j]);
            pb0[4 + j] = (short)f2bf_hw(p[4 + j]);
            pb1[j]     = (short)f2bf_hw(p[8 + j]);
            pb1[4 + j] = (short)f2bf_hw(p[12 + j]);
        }
        // ---- PV: 8 channel-tiles x 2 k-halves ----
        __builtin_amdgcn_s_setprio(1);
        MFMAG(vg0, 0);
        MFMAG(vg1, 4);
        __builtin_amdgcn_s_setprio(0);
        if (t + 1 < nt) {
            LGKM0; SCHEDB;
            SBAR;                // all waves done reading VT[rb]
            VMCNT4; SCHEDB;      // own V(t+1) stage landed (kfn stays in flight)
            SBAR;                // => everyone's V(t+1) landed
#pragma unroll
            for (int it = 0; it < 4; ++it) kfc[it] = kfn[it];
        }
    }

    // ---- fused epilogue: normalize + gamma + residual ----
    l_acc += __shfl_xor(l_acc, 16);
    l_acc += __shfl_xor(l_acc, 32);
    float inv = 1.f / l_acc;
    float gm = gamma[0];
#pragma unroll
    for (int ct = 0; ct < 8; ++ct)
#pragma unroll
        for (int r = 0; r < 4; ++r) {
            int c = wc * 128 + ct * 16 + 4 * g + r;
            size_t idx = ((size_t)(b * C_ + c)) * N_ + qb + wq * 16 + l15;
            out[idx] = gm * acc[ct][r] * inv + v_in[idx];
        }
#undef LOADG
#undef MFMAG
}

extern "C" void kernel_launch(void* const* d_in, const int* in_sizes, int n_in,
                              void* d_out, int out_size, void* d_ws, size_t ws_size,
                              hipStream_t stream) {
    (void)in_sizes; (void)n_in; (void)out_size; (void)ws_size;
    const float* v_in  = (const float*)d_in[0];
    const float* k_in  = (const float*)d_in[1];
    const float* q_in  = (const float*)d_in[2];
    const float* Wq    = (const float*)d_in[3];
    const float* bq    = (const float*)d_in[4];
    const float* Wk    = (const float*)d_in[5];
    const float* bk    = (const float*)d_in[6];
    const float* Wv    = (const float*)d_in[7];
    const float* bv    = (const float*)d_in[8];
    const float* gamma = (const float*)d_in[9];
    float* out = (float*)d_out;

    char* ws = (char*)d_ws;
    unsigned short* pvb = (unsigned short*)(ws + 0);          // 8.39 MB [b][c][m'] pi-permuted
    unsigned short* pqT = (unsigned short*)(ws + 8388608);    // 1 MB [b][n][32] (x log2e)
    unsigned short* pkT = (unsigned short*)(ws + 9437184);    // 1 MB
    unsigned short* Wqb = (unsigned short*)(ws + 10485760);   // 16 KB
    unsigned short* Wkb = (unsigned short*)(ws + 10502144);   // 16 KB
    unsigned short* Wvb = (unsigned short*)(ws + 10518528);   // 128 KB

    cast_w_k<<<320, 256, 0, stream>>>(Wq, Wk, Wv, Wqb, Wkb, Wvb);
    proj_qk_k<<<dim3(64, 4, 2), 256, 0, stream>>>(q_in, k_in, Wqb, Wkb, bq, bk, pqT, pkT);
    proj_v_k<<<dim3(256, 4), 256, 0, stream>>>(v_in, Wvb, bv, pvb);
    attn_fused_k<<<dim3(64, 1, 4), 512, 0, stream>>>(pqT, pkT, pvb, v_in, gamma, out);
}

// Round 7
// 112.283 us; speedup vs baseline: 1.0967x; 1.0967x over previous
//
#include <hip/hip_runtime.h>
#include <hip/hip_bf16.h>

typedef __attribute__((ext_vector_type(8))) short short8_t;
typedef __attribute__((ext_vector_type(4))) short short4_t;
typedef __attribute__((ext_vector_type(4))) float float4_t;

#define B_   4
#define C_   256
#define N_   4096
#define DQK  32
#define LOG2E 1.4426950408889634f

#define VMCNT4   asm volatile("s_waitcnt vmcnt(4)" ::: "memory")
#define LGKM0    asm volatile("s_waitcnt lgkmcnt(0)" ::: "memory")
#define SBAR     __builtin_amdgcn_s_barrier()
#define SCHEDB   __builtin_amdgcn_sched_barrier(0)

__device__ __forceinline__ unsigned short f2bf(float x) {
    union { float f; unsigned int u; } v; v.f = x;
    unsigned int r = v.u + 0x7FFFu + ((v.u >> 16) & 1u);   // RNE
    return (unsigned short)(r >> 16);
}
__device__ __forceinline__ unsigned short f2bf_hw(float x) {
    return __bfloat16_as_ushort(__float2bfloat16(x));      // hw RNE, pairs to cvt_pk
}

// ---------------- weight casts ----------------
__global__ __launch_bounds__(256) void cast_w_k(
        const float* __restrict__ Wq, const float* __restrict__ Wk,
        const float* __restrict__ Wv,
        unsigned short* __restrict__ Wqb, unsigned short* __restrict__ Wkb,
        unsigned short* __restrict__ Wvb) {
    int i = blockIdx.x * 256 + threadIdx.x;
    if (i < 8192)            Wqb[i] = f2bf(Wq[i]);
    else if (i < 16384)      Wkb[i - 8192] = f2bf(Wk[i - 8192]);
    else                     Wvb[i - 16384] = f2bf(Wv[i - 16384]);
}

// ---------------- pq / pk projection, reading x f32 [b][c][n] directly ----------------
// pq output pre-scaled by log2(e) so attention can use exp2 directly.
__global__ __launch_bounds__(256) void proj_qk_k(
        const float* __restrict__ q_in, const float* __restrict__ k_in,
        const unsigned short* __restrict__ Wqb, const unsigned short* __restrict__ Wkb,
        const float* __restrict__ bq, const float* __restrict__ bk,
        unsigned short* __restrict__ pqT, unsigned short* __restrict__ pkT) {
    int b = blockIdx.y, z = blockIdx.z;
    const float* X = z ? k_in : q_in;
    const unsigned short* W = z ? Wkb : Wqb;
    const float* bias = z ? bk : bq;
    unsigned short* P = z ? pkT : pqT;
    float scl = z ? 1.0f : LOG2E;
    int tid = threadIdx.x, wave = tid >> 6, lane = tid & 63, l15 = lane & 15, g = lane >> 4;
    int nb = blockIdx.x * 64 + wave * 16;
    float4_t acc0 = {0.f, 0.f, 0.f, 0.f}, acc1 = {0.f, 0.f, 0.f, 0.f};
    const float* Xcol = X + (size_t)b * C_ * N_ + nb + l15;
#pragma unroll
    for (int kk = 0; kk < 8; ++kk) {
        short8_t a;
#pragma unroll
        for (int j = 0; j < 8; ++j)
            a[j] = (short)f2bf(Xcol[(size_t)(kk * 32 + 8 * g + j) * N_]);
        short8_t b0 = *(const short8_t*)(W + (size_t)l15 * C_ + kk * 32 + 8 * g);
        short8_t b1 = *(const short8_t*)(W + (size_t)(16 + l15) * C_ + kk * 32 + 8 * g);
        acc0 = __builtin_amdgcn_mfma_f32_16x16x32_bf16(a, b0, acc0, 0, 0, 0);
        acc1 = __builtin_amdgcn_mfma_f32_16x16x32_bf16(a, b1, acc1, 0, 0, 0);
    }
#pragma unroll
    for (int r = 0; r < 4; ++r) {
        int n = nb + 4 * g + r;
        P[((size_t)b * N_ + n) * DQK + l15]      = f2bf((acc0[r] + bias[l15]) * scl);
        P[((size_t)b * N_ + n) * DQK + 16 + l15] = f2bf((acc1[r] + bias[16 + l15]) * scl);
    }
}

// ---------------- pv projection: pv[b][c][m'] = Wv x v + bv, keys pi-permuted ----------------
__global__ __launch_bounds__(256) void proj_v_k(
        const float* __restrict__ v_in, const unsigned short* __restrict__ Wvb,
        const float* __restrict__ bv, unsigned short* __restrict__ pv) {
    int b = blockIdx.y;
    int tid = threadIdx.x, wave = tid >> 6, lane = tid & 63, l15 = lane & 15, g = lane >> 4;
    int mb = blockIdx.x * 16;
    int m = mb + l15;
    int k32 = m & 31;
    int pcol = (k32 < 16) ? ((k32 >> 2) * 8 + (k32 & 3))
                          : (((k32 - 16) >> 2) * 8 + 4 + (k32 & 3));
    int mcol = (m & ~31) + pcol;
    float4_t acc[4];
#pragma unroll
    for (int i = 0; i < 4; ++i) acc[i] = (float4_t){0.f, 0.f, 0.f, 0.f};
    const float* Vcol = v_in + (size_t)b * C_ * N_ + mb + l15;
#pragma unroll
    for (int kk = 0; kk < 8; ++kk) {
        short8_t bf;
#pragma unroll
        for (int j = 0; j < 8; ++j)
            bf[j] = (short)f2bf(Vcol[(size_t)(kk * 32 + 8 * g + j) * N_]);
#pragma unroll
        for (int ct = 0; ct < 4; ++ct) {
            short8_t af = *(const short8_t*)(Wvb + (size_t)(wave * 64 + ct * 16 + l15) * C_ + kk * 32 + 8 * g);
            acc[ct] = __builtin_amdgcn_mfma_f32_16x16x32_bf16(af, bf, acc[ct], 0, 0, 0);
        }
    }
#pragma unroll
    for (int ct = 0; ct < 4; ++ct)
#pragma unroll
        for (int r = 0; r < 4; ++r) {
            int c = wave * 64 + ct * 16 + 4 * g + r;
            pv[((size_t)b * C_ + c) * N_ + mcol] = f2bf(acc[ct][r] + bv[c]);
        }
}

// ---------------- flash attention, split over keys, fat waves ----------------
// Block = 4 waves = 2 q-slices x 2 ch-halves over 64q x 256ch. Wave owns
// 32q x 128ch: acc 2x8 float4. P in registers (swapped QK^T == PV B-frag);
// per-unit V-LDS-read drops 128KB -> 64KB vs thin waves. l accumulated via
// ones-row MFMA (no VALU adds, no epilogue shuffle). KS=2 -> 512 blocks =
// 2 blocks/CU so barrier stalls overlap.
__global__ __launch_bounds__(256, 2) void attn_split_k(
        const unsigned short* __restrict__ pqT, const unsigned short* __restrict__ pkT,
        const unsigned short* __restrict__ pv,
        float* __restrict__ accP, float* __restrict__ lP, int KS) {
    __shared__ __align__(16) unsigned short VT[2][256][64];   // 64KB
    // XCD-chunked bijective swizzle: each XCD covers all 64 qb of one (s,b)
    int nqb = gridDim.x;
    int lin = blockIdx.x + nqb * (blockIdx.y + KS * blockIdx.z);
    int cpx = (nqb * KS * 4) >> 3;
    int sl  = (lin & 7) * cpx + (lin >> 3);
    int qbi = sl % nqb;
    int s   = (sl / nqb) % KS;
    int b   = sl / (nqb * KS);

    int kps = N_ / KS, ks0 = s * kps, nt = kps >> 6;
    int tid = threadIdx.x, wave = tid >> 6, lane = tid & 63, l15 = lane & 15, g = lane >> 4;
    int wq = wave & 1, wc = wave >> 1;       // q-slice (32q), ch-half (128ch)
    int qb = qbi * 64;
    int sw = (l15 & 7) << 4;
    int rl = lane >> 3, cp = lane & 7, cl = cp ^ rl;          // staging source permute

    short8_t qf[2];
#pragma unroll
    for (int qs = 0; qs < 2; ++qs)
        qf[qs] = *(const short8_t*)(pqT + ((size_t)b * N_ + qb + wq * 32 + qs * 16 + l15) * DQK + 8 * g);
    float4_t acc[2][8];
#pragma unroll
    for (int qs = 0; qs < 2; ++qs)
#pragma unroll
        for (int i = 0; i < 8; ++i) acc[qs][i] = (float4_t){0.f, 0.f, 0.f, 0.f};
    float4_t accl[2];
    accl[0] = (float4_t){0.f, 0.f, 0.f, 0.f};
    accl[1] = (float4_t){0.f, 0.f, 0.f, 0.f};
    short8_t onef;
#pragma unroll
    for (int j = 0; j < 8; ++j) onef[j] = (short)0x3F80;      // bf16 1.0
    const float4_t zero4 = {0.f, 0.f, 0.f, 0.f};
    const unsigned short* pvb = pv + (size_t)b * C_ * N_;

    // ---- prologue: stage V(0) -> buf0, load kf(0) ----
#pragma unroll
    for (int i = 0; i < 8; ++i) {
        int row0 = wave * 64 + i * 8;
        const unsigned short* src = pvb + (size_t)(row0 + rl) * N_ + ks0 + 8 * cl;
        __builtin_amdgcn_global_load_lds(
            (const __attribute__((address_space(1))) unsigned int*)(const void*)src,
            (__attribute__((address_space(3))) unsigned int*)(void*)&VT[0][row0][0], 16, 0, 0);
    }
    short8_t kfc[4];
#pragma unroll
    for (int it = 0; it < 4; ++it)
        kfc[it] = *(const short8_t*)(pkT + ((size_t)b * N_ + ks0 + 16 * it + l15) * DQK + 8 * g);
    VMCNT4; SCHEDB;          // V(0) landed (kf still in flight)
    SBAR;

    for (int t = 0; t < nt; ++t) {
        const int rb = t & 1;
        const int msn = ks0 + (t + 1) * 64;
        // stage V(t+1) -> other buffer (fire-and-forget)
        if (t + 1 < nt) {
#pragma unroll
            for (int i = 0; i < 8; ++i) {
                int row0 = wave * 64 + i * 8;
                const unsigned short* src = pvb + (size_t)(row0 + rl) * N_ + msn + 8 * cl;
                __builtin_amdgcn_global_load_lds(
                    (const __attribute__((address_space(1))) unsigned int*)(const void*)src,
                    (__attribute__((address_space(3))) unsigned int*)(void*)&VT[rb ^ 1][row0][0], 16, 0, 0);
            }
        }
        SCHEDB;
        // ---- QK: wave's 32 queries x 64 keys (swapped -> S^T) ----
        float4_t sv[2][4];
#pragma unroll
        for (int qs = 0; qs < 2; ++qs)
#pragma unroll
            for (int it = 0; it < 4; ++it)
                sv[qs][it] = __builtin_amdgcn_mfma_f32_16x16x32_bf16(kfc[it], qf[qs], zero4, 0, 0, 0);
        short8_t kfn[4];
        if (t + 1 < nt) {
#pragma unroll
            for (int it = 0; it < 4; ++it)
                kfn[it] = *(const short8_t*)(pkT + ((size_t)b * N_ + msn + 16 * it + l15) * DQK + 8 * g);
        }
        // ---- exp2 (pq pre-scaled by log2e; no max-subtraction) + pack ----
        short8_t pb[2][2];
#pragma unroll
        for (int qs = 0; qs < 2; ++qs) {
            float p[16];
#pragma unroll
            for (int it = 0; it < 4; ++it)
#pragma unroll
                for (int r = 0; r < 4; ++r)
                    p[it * 4 + r] = exp2f(sv[qs][it][r]);
#pragma unroll
            for (int j = 0; j < 4; ++j) {
                pb[qs][0][j]     = (short)f2bf_hw(p[j]);
                pb[qs][0][4 + j] = (short)f2bf_hw(p[4 + j]);
                pb[qs][1][j]     = (short)f2bf_hw(p[8 + j]);
                pb[qs][1][4 + j] = (short)f2bf_hw(p[12 + j]);
            }
        }
        // ---- PV over wave's 128-ch half: 8 chsub x (2 qsub x 2 khalf) ----
        const char* vb = (const char*)&VT[rb][0][0] + wc * 16384;
        __builtin_amdgcn_s_setprio(1);
#pragma unroll
        for (int ct = 0; ct < 8; ++ct) {
            const char* vrow = vb + (ct * 16 + l15) * 128;
            short8_t va0 = *(const short8_t*)(vrow + ((16 * g) ^ sw));
            short8_t va1 = *(const short8_t*)(vrow + ((64 + 16 * g) ^ sw));
            acc[0][ct] = __builtin_amdgcn_mfma_f32_16x16x32_bf16(va0, pb[0][0], acc[0][ct], 0, 0, 0);
            acc[0][ct] = __builtin_amdgcn_mfma_f32_16x16x32_bf16(va1, pb[0][1], acc[0][ct], 0, 0, 0);
            acc[1][ct] = __builtin_amdgcn_mfma_f32_16x16x32_bf16(va0, pb[1][0], acc[1][ct], 0, 0, 0);
            acc[1][ct] = __builtin_amdgcn_mfma_f32_16x16x32_bf16(va1, pb[1][1], acc[1][ct], 0, 0, 0);
        }
        // l-partials via ones-row MFMA: D[row,col] = sum_k P[k,col]
        accl[0] = __builtin_amdgcn_mfma_f32_16x16x32_bf16(onef, pb[0][0], accl[0], 0, 0, 0);
        accl[0] = __builtin_amdgcn_mfma_f32_16x16x32_bf16(onef, pb[0][1], accl[0], 0, 0, 0);
        accl[1] = __builtin_amdgcn_mfma_f32_16x16x32_bf16(onef, pb[1][0], accl[1], 0, 0, 0);
        accl[1] = __builtin_amdgcn_mfma_f32_16x16x32_bf16(onef, pb[1][1], accl[1], 0, 0, 0);
        __builtin_amdgcn_s_setprio(0);
        if (t + 1 < nt) {
            LGKM0; SCHEDB;
            SBAR;                // all waves done reading VT[rb]
            VMCNT4; SCHEDB;      // own V(t+1) stage landed (kfn stays in flight)
            SBAR;                // => everyone's V(t+1) landed
#pragma unroll
            for (int it = 0; it < 4; ++it) kfc[it] = kfn[it];
        }
    }

    // ---- epilogue: write partial acc + l ----
    float* accOut = accP + ((size_t)(b * KS + s) * C_) * N_;
#pragma unroll
    for (int qs = 0; qs < 2; ++qs) {
        int q = qb + wq * 32 + qs * 16 + l15;
#pragma unroll
        for (int ct = 0; ct < 8; ++ct)
#pragma unroll
            for (int r = 0; r < 4; ++r) {
                int c = wc * 128 + ct * 16 + 4 * g + r;
                accOut[(size_t)c * N_ + q] = acc[qs][ct][r];
            }
        if (wc == 0 && g == 0)
            lP[(size_t)(b * KS + s) * N_ + q] = accl[qs][0];
    }
}

// ---------------- combine splits + normalize + gamma*out + v ----------------
__global__ __launch_bounds__(256) void combine_k(
        const float* __restrict__ accP, const float* __restrict__ lP,
        const float* __restrict__ v_in, const float* __restrict__ gamma,
        float* __restrict__ out, int KS) {
    int i = blockIdx.x * 256 + threadIdx.x;
    const int nq4 = N_ / 4;
    int q0 = (i % nq4) * 4;
    int c  = (i / nq4) % C_;
    int b  = i / (nq4 * C_);
    float4_t num = {0.f, 0.f, 0.f, 0.f}, den = {0.f, 0.f, 0.f, 0.f};
    for (int s = 0; s < KS; ++s) {
        float4_t l4 = *(const float4_t*)(lP + (size_t)(b * KS + s) * N_ + q0);
        float4_t a4 = *(const float4_t*)(accP + ((size_t)(b * KS + s) * C_ + c) * N_ + q0);
#pragma unroll
        for (int j = 0; j < 4; ++j) {
            den[j] += l4[j];
            num[j] += a4[j];
        }
    }
    float gm = gamma[0];
    size_t idx = ((size_t)(b * C_ + c)) * N_ + q0;
    float4_t vi = *(const float4_t*)(v_in + idx);
    float4_t o;
#pragma unroll
    for (int j = 0; j < 4; ++j) o[j] = gm * num[j] / den[j] + vi[j];
    *(float4_t*)(out + idx) = o;
}

extern "C" void kernel_launch(void* const* d_in, const int* in_sizes, int n_in,
                              void* d_out, int out_size, void* d_ws, size_t ws_size,
                              hipStream_t stream) {
    (void)in_sizes; (void)n_in; (void)out_size;
    const float* v_in  = (const float*)d_in[0];
    const float* k_in  = (const float*)d_in[1];
    const float* q_in  = (const float*)d_in[2];
    const float* Wq    = (const float*)d_in[3];
    const float* bq    = (const float*)d_in[4];
    const float* Wk    = (const float*)d_in[5];
    const float* bk    = (const float*)d_in[6];
    const float* Wv    = (const float*)d_in[7];
    const float* bv    = (const float*)d_in[8];
    const float* gamma = (const float*)d_in[9];
    float* out = (float*)d_out;

    char* ws = (char*)d_ws;
    unsigned short* pvb = (unsigned short*)(ws + 0);          // 8.39 MB [b][c][m'] pi-permuted
    unsigned short* pqT = (unsigned short*)(ws + 8388608);    // 1 MB [b][n][32] (x log2e)
    unsigned short* pkT = (unsigned short*)(ws + 9437184);    // 1 MB
    unsigned short* Wqb = (unsigned short*)(ws + 10485760);   // 16 KB
    unsigned short* Wkb = (unsigned short*)(ws + 10502144);   // 16 KB
    unsigned short* Wvb = (unsigned short*)(ws + 10518528);   // 128 KB
    const size_t base2 = 10649600;

    int KS = 2;
    while (KS > 1) {
        size_t need = base2 + (size_t)KS * 16777216 + (size_t)KS * 262144;
        if (need <= ws_size) break;
        KS >>= 1;
    }
    float* accP = (float*)(ws + base2);                          // KS*16.78 MB [b][s][c][q]
    float* lP   = (float*)(ws + base2 + (size_t)KS * 16777216);  // KS*64 KB

    cast_w_k<<<320, 256, 0, stream>>>(Wq, Wk, Wv, Wqb, Wkb, Wvb);
    proj_qk_k<<<dim3(64, 4, 2), 256, 0, stream>>>(q_in, k_in, Wqb, Wkb, bq, bk, pqT, pkT);
    proj_v_k<<<dim3(256, 4), 256, 0, stream>>>(v_in, Wvb, bv, pvb);
    attn_split_k<<<dim3(64, KS, 4), 256, 0, stream>>>(pqT, pkT, pvb, accP, lP, KS);
    combine_k<<<4096, 256, 0, stream>>>(accP, lP, v_in, gamma, out, KS);
}

// Round 8
// 101.391 us; speedup vs baseline: 1.2145x; 1.1074x over previous
//
#include <hip/hip_runtime.h>
#include <hip/hip_bf16.h>

typedef __attribute__((ext_vector_type(8))) short short8_t;
typedef __attribute__((ext_vector_type(4))) short short4_t;
typedef __attribute__((ext_vector_type(4))) float float4_t;

#define B_   4
#define C_   256
#define N_   4096
#define DQK  32
#define LOG2E 1.4426950408889634f

#define VMCNT4   asm volatile("s_waitcnt vmcnt(4)" ::: "memory")
#define VMCNT0   asm volatile("s_waitcnt vmcnt(0)" ::: "memory")
#define LGKM0    asm volatile("s_waitcnt lgkmcnt(0)" ::: "memory")
#define SBAR     __builtin_amdgcn_s_barrier()
#define SCHEDB   __builtin_amdgcn_sched_barrier(0)

__device__ __forceinline__ unsigned short f2bf(float x) {
    union { float f; unsigned int u; } v; v.f = x;
    unsigned int r = v.u + 0x7FFFu + ((v.u >> 16) & 1u);   // RNE
    return (unsigned short)(r >> 16);
}
__device__ __forceinline__ unsigned short f2bf_hw(float x) {
    return __bfloat16_as_ushort(__float2bfloat16(x));      // hw RNE, pairs to cvt_pk
}

// ---------------- weight casts ----------------
__global__ __launch_bounds__(256) void cast_w_k(
        const float* __restrict__ Wq, const float* __restrict__ Wk,
        const float* __restrict__ Wv,
        unsigned short* __restrict__ Wqb, unsigned short* __restrict__ Wkb,
        unsigned short* __restrict__ Wvb) {
    int i = blockIdx.x * 256 + threadIdx.x;
    if (i < 8192)            Wqb[i] = f2bf(Wq[i]);
    else if (i < 16384)      Wkb[i - 8192] = f2bf(Wk[i - 8192]);
    else                     Wvb[i - 16384] = f2bf(Wv[i - 16384]);
}

// ---------------- pq / pk projection, reading x f32 [b][c][n] directly ----------------
// pq output pre-scaled by log2(e) so attention can use exp2 directly.
__global__ __launch_bounds__(256) void proj_qk_k(
        const float* __restrict__ q_in, const float* __restrict__ k_in,
        const unsigned short* __restrict__ Wqb, const unsigned short* __restrict__ Wkb,
        const float* __restrict__ bq, const float* __restrict__ bk,
        unsigned short* __restrict__ pqT, unsigned short* __restrict__ pkT) {
    int b = blockIdx.y, z = blockIdx.z;
    const float* X = z ? k_in : q_in;
    const unsigned short* W = z ? Wkb : Wqb;
    const float* bias = z ? bk : bq;
    unsigned short* P = z ? pkT : pqT;
    float scl = z ? 1.0f : LOG2E;
    int tid = threadIdx.x, wave = tid >> 6, lane = tid & 63, l15 = lane & 15, g = lane >> 4;
    int nb = blockIdx.x * 64 + wave * 16;
    float4_t acc0 = {0.f, 0.f, 0.f, 0.f}, acc1 = {0.f, 0.f, 0.f, 0.f};
    const float* Xcol = X + (size_t)b * C_ * N_ + nb + l15;
#pragma unroll
    for (int kk = 0; kk < 8; ++kk) {
        short8_t a;
#pragma unroll
        for (int j = 0; j < 8; ++j)
            a[j] = (short)f2bf(Xcol[(size_t)(kk * 32 + 8 * g + j) * N_]);
        short8_t b0 = *(const short8_t*)(W + (size_t)l15 * C_ + kk * 32 + 8 * g);
        short8_t b1 = *(const short8_t*)(W + (size_t)(16 + l15) * C_ + kk * 32 + 8 * g);
        acc0 = __builtin_amdgcn_mfma_f32_16x16x32_bf16(a, b0, acc0, 0, 0, 0);
        acc1 = __builtin_amdgcn_mfma_f32_16x16x32_bf16(a, b1, acc1, 0, 0, 0);
    }
#pragma unroll
    for (int r = 0; r < 4; ++r) {
        int n = nb + 4 * g + r;
        P[((size_t)b * N_ + n) * DQK + l15]      = f2bf((acc0[r] + bias[l15]) * scl);
        P[((size_t)b * N_ + n) * DQK + 16 + l15] = f2bf((acc1[r] + bias[16 + l15]) * scl);
    }
}

// ---------------- pv projection: pv[b][c][m'] = Wv x v + bv, keys pi-permuted ----------------
__global__ __launch_bounds__(256) void proj_v_k(
        const float* __restrict__ v_in, const unsigned short* __restrict__ Wvb,
        const float* __restrict__ bv, unsigned short* __restrict__ pv) {
    int b = blockIdx.y;
    int tid = threadIdx.x, wave = tid >> 6, lane = tid & 63, l15 = lane & 15, g = lane >> 4;
    int mb = blockIdx.x * 16;
    int m = mb + l15;
    int k32 = m & 31;
    int pcol = (k32 < 16) ? ((k32 >> 2) * 8 + (k32 & 3))
                          : (((k32 - 16) >> 2) * 8 + 4 + (k32 & 3));
    int mcol = (m & ~31) + pcol;
    float4_t acc[4];
#pragma unroll
    for (int i = 0; i < 4; ++i) acc[i] = (float4_t){0.f, 0.f, 0.f, 0.f};
    const float* Vcol = v_in + (size_t)b * C_ * N_ + mb + l15;
#pragma unroll
    for (int kk = 0; kk < 8; ++kk) {
        short8_t bf;
#pragma unroll
        for (int j = 0; j < 8; ++j)
            bf[j] = (short)f2bf(Vcol[(size_t)(kk * 32 + 8 * g + j) * N_]);
#pragma unroll
        for (int ct = 0; ct < 4; ++ct) {
            short8_t af = *(const short8_t*)(Wvb + (size_t)(wave * 64 + ct * 16 + l15) * C_ + kk * 32 + 8 * g);
            acc[ct] = __builtin_amdgcn_mfma_f32_16x16x32_bf16(af, bf, acc[ct], 0, 0, 0);
        }
    }
#pragma unroll
    for (int ct = 0; ct < 4; ++ct)
#pragma unroll
        for (int r = 0; r < 4; ++r) {
            int c = wave * 64 + ct * 16 + 4 * g + r;
            pv[((size_t)b * C_ + c) * N_ + mcol] = f2bf(acc[ct][r] + bv[c]);
        }
}

// ---------------- flash attention, split over keys, P-pipelined ----------------
// r5 structure (4 waves x 16q x 256ch, KS=2, 64-key dbuf) +:
//  - P computed one tile ahead: QK(t+1)/exp/pack overlap PV(t)'s MFMA stream
//    (ping-pong pb/kf registers, 2x-unrolled loop, no reg copies).
//  - zero per-tile address VALU: ds_read via 2 precomputed bases + imm offsets;
//    staging via 8 persistent byte-offsets (+128/tile); kf via 1 offset (+4096).
//  - l accumulated by ones-row MFMA (no VALU adds, no epilogue shuffle).
__global__ __launch_bounds__(256, 2) void attn_split_k(
        const unsigned short* __restrict__ pqT, const unsigned short* __restrict__ pkT,
        const unsigned short* __restrict__ pv,
        float* __restrict__ accP, float* __restrict__ lP, int KS) {
    __shared__ __align__(16) unsigned short VT[2][256][64];   // 64KB
    // XCD-chunked bijective swizzle: each XCD covers all 64 qb of one (s,b)
    int nqb = gridDim.x;
    int lin = blockIdx.x + nqb * (blockIdx.y + KS * blockIdx.z);
    int cpx = (nqb * KS * 4) >> 3;
    int sl  = (lin & 7) * cpx + (lin >> 3);
    int qbi = sl % nqb;
    int s   = (sl / nqb) % KS;
    int b   = sl / (nqb * KS);

    int kps = N_ / KS, ks0 = s * kps, nt = kps >> 6;
    int tid = threadIdx.x, wave = tid >> 6, lane = tid & 63, l15 = lane & 15, g = lane >> 4;
    int qb = qbi * 64;
    int sw = (l15 & 7) << 4;
    int rl = lane >> 3, cl = (lane & 7) ^ rl;                 // staging source permute

    short8_t qf = *(const short8_t*)(pqT + ((size_t)b * N_ + qb + wave * 16 + l15) * DQK + 8 * g);
    float4_t acc[16];
#pragma unroll
    for (int i = 0; i < 16; ++i) acc[i] = (float4_t){0.f, 0.f, 0.f, 0.f};
    float4_t accl = {0.f, 0.f, 0.f, 0.f};
    short8_t onef;
#pragma unroll
    for (int j = 0; j < 8; ++j) onef[j] = (short)0x3F80;      // bf16 1.0
    const float4_t zero4 = {0.f, 0.f, 0.f, 0.f};
    const unsigned short* pvb = pv + (size_t)b * C_ * N_;
    const char* pkTb = (const char*)pkT + (size_t)b * N_ * DQK * 2;

    // persistent offsets (bytes)
    unsigned soff[8];
#pragma unroll
    for (int i = 0; i < 8; ++i)
        soff[i] = (unsigned)(((wave * 64 + i * 8 + rl) * N_ + ks0 + 8 * cl) * 2);
    unsigned koff = (unsigned)(((ks0 + l15) * DQK + 8 * g) * 2);
    // V-fragment read bases (imm offset = ct*2048 + rb*32768)
    int off1 = (16 * g) ^ sw, off2 = (64 + 16 * g) ^ sw;
    const char* vbA = (const char*)&VT[0][0][0] + l15 * 128 + off1;
    const char* vbB = (const char*)&VT[0][0][0] + l15 * 128 + off2;

#define STAGE(RBUF)                                                           \
    _Pragma("unroll")                                                         \
    for (int i_ = 0; i_ < 8; ++i_) {                                          \
        __builtin_amdgcn_global_load_lds(                                     \
            (const __attribute__((address_space(1))) unsigned int*)(const void*)((const char*)pvb + soff[i_]), \
            (__attribute__((address_space(3))) unsigned int*)(void*)&VT[RBUF][wave * 64 + i_ * 8][0], 16, 0, 0); \
    }                                                                          \
    _Pragma("unroll")                                                         \
    for (int i_ = 0; i_ < 8; ++i_) soff[i_] += 128;

#define KFLOAD(DST)                                                           \
    _Pragma("unroll")                                                         \
    for (int it_ = 0; it_ < 4; ++it_)                                         \
        DST[it_] = *(const short8_t*)(pkTb + koff + it_ * 1024);              \
    koff += 4096;

#define QKEXP(KF, PN0, PN1)                                                   \
    {                                                                          \
        float4_t sv_[4];                                                       \
        _Pragma("unroll")                                                      \
        for (int it_ = 0; it_ < 4; ++it_)                                      \
            sv_[it_] = __builtin_amdgcn_mfma_f32_16x16x32_bf16(KF[it_], qf, zero4, 0, 0, 0); \
        float p_[16];                                                          \
        _Pragma("unroll")                                                      \
        for (int it_ = 0; it_ < 4; ++it_)                                      \
            _Pragma("unroll")                                                  \
            for (int r_ = 0; r_ < 4; ++r_)                                     \
                p_[it_ * 4 + r_] = exp2f(sv_[it_][r_]);                        \
        _Pragma("unroll")                                                      \
        for (int j_ = 0; j_ < 4; ++j_) {                                       \
            PN0[j_]     = (short)f2bf_hw(p_[j_]);                              \
            PN0[4 + j_] = (short)f2bf_hw(p_[4 + j_]);                          \
            PN1[j_]     = (short)f2bf_hw(p_[8 + j_]);                          \
            PN1[4 + j_] = (short)f2bf_hw(p_[12 + j_]);                         \
        }                                                                      \
    }

#define PVPH(RB, PC0, PC1)                                                    \
    __builtin_amdgcn_s_setprio(1);                                            \
    _Pragma("unroll")                                                         \
    for (int ct_ = 0; ct_ < 16; ++ct_) {                                      \
        short8_t va0_ = *(const short8_t*)(vbA + (RB) * 32768 + ct_ * 2048);  \
        short8_t va1_ = *(const short8_t*)(vbB + (RB) * 32768 + ct_ * 2048);  \
        acc[ct_] = __builtin_amdgcn_mfma_f32_16x16x32_bf16(va0_, PC0, acc[ct_], 0, 0, 0); \
        acc[ct_] = __builtin_amdgcn_mfma_f32_16x16x32_bf16(va1_, PC1, acc[ct_], 0, 0, 0); \
    }                                                                          \
    accl = __builtin_amdgcn_mfma_f32_16x16x32_bf16(onef, PC0, accl, 0, 0, 0); \
    accl = __builtin_amdgcn_mfma_f32_16x16x32_bf16(onef, PC1, accl, 0, 0, 0); \
    __builtin_amdgcn_s_setprio(0);

// BODY(tile TT): stage V(TT+1); prefetch kf(TT+2); QK(TT+1)->PBN; PV(TT) with PBC.
#define BODY(RB, KFC, KFN, PC0, PC1, PN0, PN1, TT)                            \
    if ((TT) + 1 < nt) { STAGE(RB ^ 1) }                                      \
    SCHEDB;                                                                   \
    KFLOAD(KFN)                                                               \
    QKEXP(KFC, PN0, PN1)                                                      \
    PVPH(RB, PC0, PC1)                                                        \
    LGKM0; SCHEDB;                                                            \
    SBAR;                                                                     \
    VMCNT4; SCHEDB;                                                           \
    SBAR;

    // ---- prologue: stage V(0); kf(0),kf(1); pb(0) ----
    short8_t kfA[4], kfB[4];
    short8_t pbA0, pbA1, pbB0, pbB1;
    STAGE(0)
    SCHEDB;
    KFLOAD(kfB)          // kf(0)
    KFLOAD(kfA)          // kf(1)
    VMCNT0; SCHEDB;
    QKEXP(kfB, pbB0, pbB1)   // pb(0)
    SBAR;

    for (int t = 0; t < nt; t += 2) {
        BODY(0, kfA, kfB, pbB0, pbB1, pbA0, pbA1, t)
        BODY(1, kfB, kfA, pbA0, pbA1, pbB0, pbB1, t + 1)
    }

    // ---- epilogue: l from ones-MFMA (all rows equal), partial acc ----
    if (g == 0)
        lP[(size_t)(b * KS + s) * N_ + qb + wave * 16 + l15] = accl[0];
    float* accOut = accP + ((size_t)(b * KS + s) * C_) * N_;
#pragma unroll
    for (int ct = 0; ct < 16; ++ct)
#pragma unroll
        for (int r = 0; r < 4; ++r) {
            int c = ct * 16 + 4 * g + r;
            accOut[(size_t)c * N_ + qb + wave * 16 + l15] = acc[ct][r];
        }
#undef STAGE
#undef KFLOAD
#undef QKEXP
#undef PVPH
#undef BODY
}

// ---------------- combine splits + normalize + gamma*out + v ----------------
__global__ __launch_bounds__(256) void combine_k(
        const float* __restrict__ accP, const float* __restrict__ lP,
        const float* __restrict__ v_in, const float* __restrict__ gamma,
        float* __restrict__ out, int KS) {
    int i = blockIdx.x * 256 + threadIdx.x;
    const int nq4 = N_ / 4;
    int q0 = (i % nq4) * 4;
    int c  = (i / nq4) % C_;
    int b  = i / (nq4 * C_);
    float4_t num = {0.f, 0.f, 0.f, 0.f}, den = {0.f, 0.f, 0.f, 0.f};
    for (int s = 0; s < KS; ++s) {
        float4_t l4 = *(const float4_t*)(lP + (size_t)(b * KS + s) * N_ + q0);
        float4_t a4 = *(const float4_t*)(accP + ((size_t)(b * KS + s) * C_ + c) * N_ + q0);
#pragma unroll
        for (int j = 0; j < 4; ++j) {
            den[j] += l4[j];
            num[j] += a4[j];
        }
    }
    float gm = gamma[0];
    size_t idx = ((size_t)(b * C_ + c)) * N_ + q0;
    float4_t vi = *(const float4_t*)(v_in + idx);
    float4_t o;
#pragma unroll
    for (int j = 0; j < 4; ++j) o[j] = gm * num[j] / den[j] + vi[j];
    *(float4_t*)(out + idx) = o;
}

extern "C" void kernel_launch(void* const* d_in, const int* in_sizes, int n_in,
                              void* d_out, int out_size, void* d_ws, size_t ws_size,
                              hipStream_t stream) {
    (void)in_sizes; (void)n_in; (void)out_size;
    const float* v_in  = (const float*)d_in[0];
    const float* k_in  = (const float*)d_in[1];
    const float* q_in  = (const float*)d_in[2];
    const float* Wq    = (const float*)d_in[3];
    const float* bq    = (const float*)d_in[4];
    const float* Wk    = (const float*)d_in[5];
    const float* bk    = (const float*)d_in[6];
    const float* Wv    = (const float*)d_in[7];
    const float* bv    = (const float*)d_in[8];
    const float* gamma = (const float*)d_in[9];
    float* out = (float*)d_out;

    char* ws = (char*)d_ws;
    unsigned short* pvb = (unsigned short*)(ws + 0);          // 8.39 MB [b][c][m'] pi-permuted
    unsigned short* pqT = (unsigned short*)(ws + 8388608);    // 1 MB [b][n][32] (x log2e)
    unsigned short* pkT = (unsigned short*)(ws + 9437184);    // 1 MB + 16 KB pad (pipelined overread)
    unsigned short* Wqb = (unsigned short*)(ws + 10502144);   // 16 KB
    unsigned short* Wkb = (unsigned short*)(ws + 10518528);   // 16 KB
    unsigned short* Wvb = (unsigned short*)(ws + 10534912);   // 128 KB
    const size_t base2 = 10665984;

    int KS = 2;
    while (KS > 1) {
        size_t need = base2 + (size_t)KS * 16777216 + (size_t)KS * 262144;
        if (need <= ws_size) break;
        KS >>= 1;
    }
    float* accP = (float*)(ws + base2);                          // KS*16.78 MB [b][s][c][q]
    float* lP   = (float*)(ws + base2 + (size_t)KS * 16777216);  // KS*64 KB

    cast_w_k<<<320, 256, 0, stream>>>(Wq, Wk, Wv, Wqb, Wkb, Wvb);
    proj_qk_k<<<dim3(64, 4, 2), 256, 0, stream>>>(q_in, k_in, Wqb, Wkb, bq, bk, pqT, pkT);
    proj_v_k<<<dim3(256, 4), 256, 0, stream>>>(v_in, Wvb, bv, pvb);
    attn_split_k<<<dim3(64, KS, 4), 256, 0, stream>>>(pqT, pkT, pvb, accP, lP, KS);
    combine_k<<<4096, 256, 0, stream>>>(accP, lP, v_in, gamma, out, KS);
}